// Round 7
// baseline (97.670 us; speedup 1.0000x reference)
//
#include <hip/hip_runtime.h>
#include <hip/hip_bf16.h>

#define Bb 512
#define Tt 512
#define Kk 64
#define START_TAG 62
#define STOP_TAG 63
#define LN2F 0.69314718055994530942f
#define LOG2E 1.44269504088896340736f

typedef __attribute__((ext_vector_type(8))) short bf16x8;  // 8 bf16 in 4 VGPRs
typedef __attribute__((ext_vector_type(4))) float f32x4;   // MFMA C/D

__device__ inline short f2bf(float x) {
    __hip_bfloat16 h = __float2bfloat16(x);
    short s; __builtin_memcpy(&s, &h, 2); return s;
}
// pack 2 f32 -> 2 bf16 in one instruction
__device__ inline unsigned cvtpk(float lo, float hi) {
    unsigned r;
    asm("v_cvt_pk_bf16_f32 %0, %1, %2" : "=v"(r) : "v"(lo), "v"(hi));
    return r;
}

// One sequence per 64-lane wave; alpha recursion as MFMA matvec in exp-space.
// Layout (HW-verified r4/r5, absmax 0.0): tag tau(c,r)=32c+16*(r>=4)+4g+(r&3)
// on both A and B sides; D tile i reg r = tag 16i+4g+r -> D feeds next B with
// register moves only.
// Round-7 fix: round 6's rescale controller set each new k to the FULL probe
// exponent while two earlier corrections (kq1, kemb) were still in flight ->
// ~2x steady-state overcorrection -> oscillation -> probe underflows to 0 ->
// k=-127 -> exp2 overflow -> NaN. New k must be exponent MINUS pending
// corrections; clamped +-100 as an overflow guard (ktot accounting is exact
// for any k-sequence, so the clamp never affects correctness).
__global__ __launch_bounds__(64, 1) void crf_forward_mfma(
    const float* __restrict__ feats,        // (B,T,K)
    const float* __restrict__ transitions,  // (K,K), trans[i,j] = score j->i
    const int* __restrict__ lengths,        // (B,)
    float* __restrict__ fwd_out)            // (B,)
{
    const int b   = blockIdx.x;
    const int l   = threadIdx.x;
    const int row = l & 15;   // A row / D col
    const int g   = l >> 4;   // k-group

    // fr banks: fr(t) in natural layout (lane = tag), double-buffered.
    __shared__ __align__(16) float frl[2][Kk];

    // A fragments: A[i][c] slot r = exp(trans[16i+row][tau(c,r)])
    bf16x8 A00, A01, A10, A11, A20, A21, A30, A31, S0, S1;
#define MKA(Av, i, c) {                                                       \
    const float* p = transitions + (16*(i)+row)*Kk + 32*(c) + 4*g;            \
    float4 lo = *(const float4*)p; float4 hi = *(const float4*)(p + 16);      \
    Av[0]=f2bf(__expf(lo.x)); Av[1]=f2bf(__expf(lo.y));                       \
    Av[2]=f2bf(__expf(lo.z)); Av[3]=f2bf(__expf(lo.w));                       \
    Av[4]=f2bf(__expf(hi.x)); Av[5]=f2bf(__expf(hi.y));                       \
    Av[6]=f2bf(__expf(hi.z)); Av[7]=f2bf(__expf(hi.w)); }
    MKA(A00,0,0) MKA(A01,0,1) MKA(A10,1,0) MKA(A11,1,1)
    MKA(A20,2,0) MKA(A21,2,1) MKA(A30,3,0) MKA(A31,3,1)
#undef MKA
    // Terminal fragments: row 0 = exp(trans[STOP][tau]), rows 1..15 = 0
#define MKS(Av, c) {                                                          \
    const float* p = transitions + STOP_TAG*Kk + 32*(c) + 4*g;                \
    float4 lo = *(const float4*)p; float4 hi = *(const float4*)(p + 16);      \
    const bool z = (row == 0);                                                \
    Av[0]=z?f2bf(__expf(lo.x)):(short)0; Av[1]=z?f2bf(__expf(lo.y)):(short)0; \
    Av[2]=z?f2bf(__expf(lo.z)):(short)0; Av[3]=z?f2bf(__expf(lo.w)):(short)0; \
    Av[4]=z?f2bf(__expf(hi.x)):(short)0; Av[5]=z?f2bf(__expf(hi.y)):(short)0; \
    Av[6]=z?f2bf(__expf(hi.z)):(short)0; Av[7]=z?f2bf(__expf(hi.w)):(short)0; }
    MKS(S0,0) MKS(S1,1)
#undef MKS

    const int len = lengths[b];
    const float* fb = feats + (size_t)b * Tt * Kk + l;  // natural: lane = tag

    // alpha0: 1 at START=62 -> B1 slot 6, g=3
    bf16x8 B0 = {}; bf16x8 B1 = {};
    if (g == 3) B1[6] = (short)0x3F80;  // bf16(1.0)

    const float* bank0 = &frl[0][4 * g];
    const float* bank1 = &frl[1][4 * g];

    // ---- prologue ----
    const float fr0_ = __builtin_amdgcn_exp2f(fb[0]      * LOG2E);
    const float fr1_ = __builtin_amdgcn_exp2f(fb[Kk]     * LOG2E);
    const float fr2_ = __builtin_amdgcn_exp2f(fb[2 * Kk] * LOG2E);
    const float fr3_ = __builtin_amdgcn_exp2f(fb[3 * Kk] * LOG2E);
    f32x4 FA0, FA1, FA2, FA3, FB0, FB1, FB2, FB3;
    frl[0][l] = fr0_;
    frl[1][l] = fr1_;
    __builtin_amdgcn_wave_barrier();
    FA0 = *(const f32x4*)(bank0);      FA1 = *(const f32x4*)(bank0 + 16);
    FA2 = *(const f32x4*)(bank0 + 32); FA3 = *(const f32x4*)(bank0 + 48);
    FB0 = *(const f32x4*)(bank1);      FB1 = *(const f32x4*)(bank1 + 16);
    FB2 = *(const f32x4*)(bank1 + 32); FB3 = *(const f32x4*)(bank1 + 48);
    __builtin_amdgcn_wave_barrier();
    frl[0][l] = fr2_;   // after FA/FB reads (same-wave DS FIFO)
    frl[1][l] = fr3_;
    __builtin_amdgcn_wave_barrier();

    // emit ring, 8 deep: er0..er7 = rows t+4..t+11 (rows always allocated)
    float er0 = fb[4 * Kk],  er1 = fb[5 * Kk],  er2 = fb[6 * Kk],  er3 = fb[7 * Kk];
    float er4 = fb[8 * Kk],  er5 = fb[9 * Kk],  er6 = fb[10 * Kk], er7 = fb[11 * Kk];

    const f32x4 zz = {0.f, 0.f, 0.f, 0.f};
    int ktot = 0;
    int kq0 = 0, kq1 = 0, kemb = 0;  // k embedded in fr(2j), fr(2j+2), next write
    float probeA, probeB;

#define MFMA16(Aa, Bx, Cc) __builtin_amdgcn_mfma_f32_16x16x32_bf16(Aa, Bx, Cc, 0, 0, 0)

#define STEP(F0_, F1_, F2_, F3_, PR) {                                        \
    f32x4 d0 = MFMA16(A00, B0, zz); d0 = MFMA16(A01, B1, d0);                 \
    f32x4 d1 = MFMA16(A10, B0, zz); d1 = MFMA16(A11, B1, d1);                 \
    f32x4 d2 = MFMA16(A20, B0, zz); d2 = MFMA16(A21, B1, d2);                 \
    f32x4 d3 = MFMA16(A30, B0, zz); d3 = MFMA16(A31, B1, d3);                 \
    f32x4 m0 = d0 * F0_, m1 = d1 * F1_, m2 = d2 * F2_, m3 = d3 * F3_;         \
    PR = m0[0];                                                               \
    union { unsigned u[4]; bf16x8 v; } nb0, nb1;                              \
    nb0.u[0] = cvtpk(m0[0], m0[1]); nb0.u[1] = cvtpk(m0[2], m0[3]);           \
    nb0.u[2] = cvtpk(m1[0], m1[1]); nb0.u[3] = cvtpk(m1[2], m1[3]);           \
    nb1.u[0] = cvtpk(m2[0], m2[1]); nb1.u[1] = cvtpk(m2[2], m2[3]);           \
    nb1.u[2] = cvtpk(m3[0], m3[1]); nb1.u[3] = cvtpk(m3[2], m3[3]);           \
    B0 = nb0.v; B1 = nb1.v; }

    int t = 0;
    for (; t + 1 < len; t += 2) {
        // ---- slot A (step t) ----
        f32x4 NA0 = *(const f32x4*)(bank0);      f32x4 NA1 = *(const f32x4*)(bank0 + 16);
        f32x4 NA2 = *(const f32x4*)(bank0 + 32); f32x4 NA3 = *(const f32x4*)(bank0 + 48);
        STEP(FA0, FA1, FA2, FA3, probeA)
        ktot += kq0;
        const float frA = __builtin_amdgcn_exp2f(fmaf(er0, LOG2E, -(float)kemb));
        __builtin_amdgcn_wave_barrier();
        frl[0][l] = frA;               // fr(t+4), embeds kemb (read NA preceded)
        __builtin_amdgcn_wave_barrier();
        // ---- slot B (step t+1) ----
        f32x4 NB0 = *(const f32x4*)(bank1);      f32x4 NB1 = *(const f32x4*)(bank1 + 16);
        f32x4 NB2 = *(const f32x4*)(bank1 + 32); f32x4 NB3 = *(const f32x4*)(bank1 + 48);
        STEP(FB0, FB1, FB2, FB3, probeB)
        const float frB = __builtin_amdgcn_exp2f(er1 * LOG2E);
        __builtin_amdgcn_wave_barrier();
        frl[1][l] = frB;               // fr(t+5)
        __builtin_amdgcn_wave_barrier();
        // ---- bookkeeping (off the MFMA chain) ----
        // New correction = probe exponent MINUS corrections still in flight
        // (kq1 -> fr(t+2), kemb -> fr(t+4), neither consumed at probe time).
        // Round 6 omitted the subtraction -> divergent feedback -> NaN.
        const unsigned pb =
            (unsigned)__builtin_amdgcn_readfirstlane(__float_as_int(probeB));
        int knew = ((int)((pb >> 23) & 255) - 127) - kq1 - kemb;
        knew = (knew > 100) ? 100 : ((knew < -100) ? -100 : knew);
        kq0 = kq1; kq1 = kemb; kemb = knew;
        FA0 = NA0; FA1 = NA1; FA2 = NA2; FA3 = NA3;   // register renames
        FB0 = NB0; FB1 = NB1; FB2 = NB2; FB3 = NB3;
        // ring shift + 2 loads (~3 iterations ahead of use)
        er0 = er2; er1 = er3; er2 = er4; er3 = er5; er4 = er6; er5 = er7;
        const int r0 = (t + 12 < Tt) ? t + 12 : Tt - 1;
        const int r1 = (t + 13 < Tt) ? t + 13 : Tt - 1;
        er6 = fb[r0 * Kk]; er7 = fb[r1 * Kk];
        (void)probeA;
    }

    // tail (len odd): one step with FA = F(t)
    if (t < len) {
        STEP(FA0, FA1, FA2, FA3, probeA)
        ktot += kq0;
        (void)probeA;
    }

    // terminal: d4 row0 = etstop . alpha (current scale 2^-ktot)
    f32x4 d4 = MFMA16(S0, B0, zz); d4 = MFMA16(S1, B1, d4);
    const float term = __uint_as_float(
        (unsigned)__builtin_amdgcn_readfirstlane(__float_as_int(d4[0])));
    if (l == 0) fwd_out[b] = (float)ktot * LN2F + logf(term);
#undef STEP
#undef MFMA16
}

// Gold path score: fully parallel over t (lane-strided).
__global__ __launch_bounds__(64) void crf_gold_kernel(
    const float* __restrict__ feats,
    const float* __restrict__ transitions,
    const int* __restrict__ tags,     // (B,T)
    const int* __restrict__ lengths,  // (B,)
    float* __restrict__ gold_out)     // (B,)
{
    const int b = blockIdx.x;
    const int lane = threadIdx.x;
    const int len = lengths[b];
    const int* tb = tags + b * Tt;
    const float* fb = feats + (size_t)b * Tt * Kk;

    float acc = 0.f;
    for (int t = lane; t < len; t += 64) {
        const int tg = tb[t];
        const int prev = (t == 0) ? START_TAG : tb[t - 1];
        acc += transitions[tg * Kk + prev];  // score prev -> tg
        acc += fb[t * Kk + tg];              // emission
    }
    if (lane == 0) acc += transitions[STOP_TAG * Kk + tb[len - 1]];  // last -> STOP
#pragma unroll
    for (int off = 32; off >= 1; off >>= 1) acc += __shfl_xor(acc, off, 64);
    if (lane == 0) gold_out[b] = acc;
}

__global__ __launch_bounds__(512) void crf_reduce_kernel(
    const float* __restrict__ fwd, const float* __restrict__ gold,
    float* __restrict__ out)
{
    const int i = threadIdx.x;  // 0..511
    float v = fwd[i] - gold[i];
#pragma unroll
    for (int off = 32; off >= 1; off >>= 1) v += __shfl_xor(v, off, 64);
    __shared__ float ws[8];
    if ((i & 63) == 0) ws[i >> 6] = v;
    __syncthreads();
    if (i < 8) {
        float s = ws[i];
#pragma unroll
        for (int off = 4; off >= 1; off >>= 1) s += __shfl_xor(s, off, 8);
        if (i == 0) out[0] = s * (1.0f / (float)Bb);
    }
}

extern "C" void kernel_launch(void* const* d_in, const int* in_sizes, int n_in,
                              void* d_out, int out_size, void* d_ws, size_t ws_size,
                              hipStream_t stream) {
    const float* feats = (const float*)d_in[0];
    const float* trans = (const float*)d_in[1];
    const int* tags = (const int*)d_in[2];
    const int* lengths = (const int*)d_in[3];
    float* out = (float*)d_out;
    float* fwd = (float*)d_ws;
    float* gold = fwd + Bb;

    crf_gold_kernel<<<Bb, 64, 0, stream>>>(feats, trans, tags, lengths, gold);
    crf_forward_mfma<<<Bb, 64, 0, stream>>>(feats, trans, lengths, fwd);
    crf_reduce_kernel<<<1, 512, 0, stream>>>(fwd, gold, out);
}

// Round 8
// 97.140 us; speedup vs baseline: 1.0055x; 1.0055x over previous
//
#include <hip/hip_runtime.h>
#include <hip/hip_bf16.h>

#define Bb 512
#define Tt 512
#define Kk 64
#define START_TAG 62
#define STOP_TAG 63
#define LN2F 0.69314718055994530942f
#define LOG2E 1.44269504088896340736f

typedef __attribute__((ext_vector_type(8))) short bf16x8;  // 8 bf16 in 4 VGPRs
typedef __attribute__((ext_vector_type(4))) float f32x4;   // MFMA C/D

__device__ inline short f2bf(float x) {
    __hip_bfloat16 h = __float2bfloat16(x);
    short s; __builtin_memcpy(&s, &h, 2); return s;
}
// pack 2 f32 -> 2 bf16 in one instruction
__device__ inline unsigned cvtpk(float lo, float hi) {
    unsigned r;
    asm("v_cvt_pk_bf16_f32 %0, %1, %2" : "=v"(r) : "v"(lo), "v"(hi));
    return r;
}

// One sequence per 64-lane wave; alpha recursion as MFMA matvec in exp-space.
// Layout (HW-verified r4-r7, absmax 0.0): tag tau(c,r)=32c+16*(r>=4)+4g+(r&3)
// on both A and B sides; D tile i reg r = tag 16i+4g+r -> D feeds next B with
// register moves only.
// Round-8 change: ONE wave_barrier per iteration instead of four. r5 vs r7
// proved the stall is neither vmcnt nor lgkmcnt latency (prefetch depth was
// irrelevant); the barriers themselves were forfeiting ~100 cyc/slot of
// issue/stall overlap by fencing independent work (LDS reads, exp2, ring
// loads, scalar bookkeeping) out of the MFMA drain windows. DS-FIFO
// correctness only needs reads-before-writes per iteration: one barrier.
__global__ __launch_bounds__(64, 1) void crf_forward_mfma(
    const float* __restrict__ feats,        // (B,T,K)
    const float* __restrict__ transitions,  // (K,K), trans[i,j] = score j->i
    const int* __restrict__ lengths,        // (B,)
    float* __restrict__ fwd_out)            // (B,)
{
    const int b   = blockIdx.x;
    const int l   = threadIdx.x;
    const int row = l & 15;   // A row / D col
    const int g   = l >> 4;   // k-group

    // fr banks: fr(t) in natural layout (lane = tag), double-buffered.
    __shared__ __align__(16) float frl[2][Kk];

    // A fragments: A[i][c] slot r = exp(trans[16i+row][tau(c,r)])
    bf16x8 A00, A01, A10, A11, A20, A21, A30, A31, S0, S1;
#define MKA(Av, i, c) {                                                       \
    const float* p = transitions + (16*(i)+row)*Kk + 32*(c) + 4*g;            \
    float4 lo = *(const float4*)p; float4 hi = *(const float4*)(p + 16);      \
    Av[0]=f2bf(__expf(lo.x)); Av[1]=f2bf(__expf(lo.y));                       \
    Av[2]=f2bf(__expf(lo.z)); Av[3]=f2bf(__expf(lo.w));                       \
    Av[4]=f2bf(__expf(hi.x)); Av[5]=f2bf(__expf(hi.y));                       \
    Av[6]=f2bf(__expf(hi.z)); Av[7]=f2bf(__expf(hi.w)); }
    MKA(A00,0,0) MKA(A01,0,1) MKA(A10,1,0) MKA(A11,1,1)
    MKA(A20,2,0) MKA(A21,2,1) MKA(A30,3,0) MKA(A31,3,1)
#undef MKA
    // Terminal fragments: row 0 = exp(trans[STOP][tau]), rows 1..15 = 0
#define MKS(Av, c) {                                                          \
    const float* p = transitions + STOP_TAG*Kk + 32*(c) + 4*g;                \
    float4 lo = *(const float4*)p; float4 hi = *(const float4*)(p + 16);      \
    const bool z = (row == 0);                                                \
    Av[0]=z?f2bf(__expf(lo.x)):(short)0; Av[1]=z?f2bf(__expf(lo.y)):(short)0; \
    Av[2]=z?f2bf(__expf(lo.z)):(short)0; Av[3]=z?f2bf(__expf(lo.w)):(short)0; \
    Av[4]=z?f2bf(__expf(hi.x)):(short)0; Av[5]=z?f2bf(__expf(hi.y)):(short)0; \
    Av[6]=z?f2bf(__expf(hi.z)):(short)0; Av[7]=z?f2bf(__expf(hi.w)):(short)0; }
    MKS(S0,0) MKS(S1,1)
#undef MKS

    const int len = lengths[b];
    const float* fb = feats + (size_t)b * Tt * Kk + l;  // natural: lane = tag

    // alpha0: 1 at START=62 -> B1 slot 6, g=3
    bf16x8 B0 = {}; bf16x8 B1 = {};
    if (g == 3) B1[6] = (short)0x3F80;  // bf16(1.0)

    const float* bank0 = &frl[0][4 * g];
    const float* bank1 = &frl[1][4 * g];

    // ---- prologue ----
    const float fr0_ = __builtin_amdgcn_exp2f(fb[0]      * LOG2E);
    const float fr1_ = __builtin_amdgcn_exp2f(fb[Kk]     * LOG2E);
    const float fr2_ = __builtin_amdgcn_exp2f(fb[2 * Kk] * LOG2E);
    const float fr3_ = __builtin_amdgcn_exp2f(fb[3 * Kk] * LOG2E);
    f32x4 FA0, FA1, FA2, FA3, FB0, FB1, FB2, FB3;
    frl[0][l] = fr0_;
    frl[1][l] = fr1_;
    __builtin_amdgcn_wave_barrier();
    FA0 = *(const f32x4*)(bank0);      FA1 = *(const f32x4*)(bank0 + 16);
    FA2 = *(const f32x4*)(bank0 + 32); FA3 = *(const f32x4*)(bank0 + 48);
    FB0 = *(const f32x4*)(bank1);      FB1 = *(const f32x4*)(bank1 + 16);
    FB2 = *(const f32x4*)(bank1 + 32); FB3 = *(const f32x4*)(bank1 + 48);
    __builtin_amdgcn_wave_barrier();
    frl[0][l] = fr2_;   // after FA/FB reads (same-wave DS FIFO)
    frl[1][l] = fr3_;
    __builtin_amdgcn_wave_barrier();

    // emit ring, 4 deep: er0..er3 = rows t+4..t+7 (rows always allocated;
    // er0 consumed 2 backedges after its load -> ~500 cyc of cover)
    float er0 = fb[4 * Kk], er1 = fb[5 * Kk], er2 = fb[6 * Kk], er3 = fb[7 * Kk];

    const f32x4 zz = {0.f, 0.f, 0.f, 0.f};
    int ktot = 0;
    int kq0 = 0, kq1 = 0, kemb = 0;  // k embedded in fr(2j), fr(2j+2), next write
    float probeA, probeB;

#define MFMA16(Aa, Bx, Cc) __builtin_amdgcn_mfma_f32_16x16x32_bf16(Aa, Bx, Cc, 0, 0, 0)

#define STEP(F0_, F1_, F2_, F3_, PR) {                                        \
    f32x4 d0 = MFMA16(A00, B0, zz); d0 = MFMA16(A01, B1, d0);                 \
    f32x4 d1 = MFMA16(A10, B0, zz); d1 = MFMA16(A11, B1, d1);                 \
    f32x4 d2 = MFMA16(A20, B0, zz); d2 = MFMA16(A21, B1, d2);                 \
    f32x4 d3 = MFMA16(A30, B0, zz); d3 = MFMA16(A31, B1, d3);                 \
    f32x4 m0 = d0 * F0_, m1 = d1 * F1_, m2 = d2 * F2_, m3 = d3 * F3_;         \
    PR = m0[0];                                                               \
    union { unsigned u[4]; bf16x8 v; } nb0, nb1;                              \
    nb0.u[0] = cvtpk(m0[0], m0[1]); nb0.u[1] = cvtpk(m0[2], m0[3]);           \
    nb0.u[2] = cvtpk(m1[0], m1[1]); nb0.u[3] = cvtpk(m1[2], m1[3]);           \
    nb1.u[0] = cvtpk(m2[0], m2[1]); nb1.u[1] = cvtpk(m2[2], m2[3]);           \
    nb1.u[2] = cvtpk(m3[0], m3[1]); nb1.u[3] = cvtpk(m3[2], m3[3]);           \
    B0 = nb0.v; B1 = nb1.v; }

    int t = 0;
    for (; t + 1 < len; t += 2) {
        // Next iteration's F (bank0 = fr(t+2), bank1 = fr(t+3)) + write data.
        // All of this is chain-independent: the scheduler may interleave it
        // into the STEP A/B MFMA drain windows (no fences until the writes).
        f32x4 NA0 = *(const f32x4*)(bank0);      f32x4 NA1 = *(const f32x4*)(bank0 + 16);
        f32x4 NA2 = *(const f32x4*)(bank0 + 32); f32x4 NA3 = *(const f32x4*)(bank0 + 48);
        f32x4 NB0 = *(const f32x4*)(bank1);      f32x4 NB1 = *(const f32x4*)(bank1 + 16);
        f32x4 NB2 = *(const f32x4*)(bank1 + 32); f32x4 NB3 = *(const f32x4*)(bank1 + 48);
        const float frA = __builtin_amdgcn_exp2f(fmaf(er0, LOG2E, -(float)kemb));
        const float frB = __builtin_amdgcn_exp2f(er1 * LOG2E);

        STEP(FA0, FA1, FA2, FA3, probeA)
        STEP(FB0, FB1, FB2, FB3, probeB)

        __builtin_amdgcn_wave_barrier();   // all DS reads above precede writes
        frl[0][l] = frA;                   // fr(t+4), embeds kemb
        frl[1][l] = frB;                   // fr(t+5)

        // ---- bookkeeping (off the MFMA chain) ----
        ktot += kq0;
        const unsigned pb =
            (unsigned)__builtin_amdgcn_readfirstlane(__float_as_int(probeB));
        int knew = ((int)((pb >> 23) & 255) - 127) - kq1 - kemb;  // minus in-flight
        knew = (knew > 100) ? 100 : ((knew < -100) ? -100 : knew);
        kq0 = kq1; kq1 = kemb; kemb = knew;
        FA0 = NA0; FA1 = NA1; FA2 = NA2; FA3 = NA3;   // register renames
        FB0 = NB0; FB1 = NB1; FB2 = NB2; FB3 = NB3;
        er0 = er2; er1 = er3;
        const int r0 = (t + 8 < Tt) ? t + 8 : Tt - 1;
        const int r1 = (t + 9 < Tt) ? t + 9 : Tt - 1;
        er2 = fb[r0 * Kk]; er3 = fb[r1 * Kk];
        (void)probeA;
    }

    // tail (len odd): one step with FA = F(t)
    if (t < len) {
        STEP(FA0, FA1, FA2, FA3, probeA)
        ktot += kq0;
        (void)probeA;
    }

    // terminal: d4 row0 = etstop . alpha (current scale 2^-ktot)
    f32x4 d4 = MFMA16(S0, B0, zz); d4 = MFMA16(S1, B1, d4);
    const float term = __uint_as_float(
        (unsigned)__builtin_amdgcn_readfirstlane(__float_as_int(d4[0])));
    if (l == 0) fwd_out[b] = (float)ktot * LN2F + logf(term);
#undef STEP
#undef MFMA16
}

// Gold path score: fully parallel over t (lane-strided).
__global__ __launch_bounds__(64) void crf_gold_kernel(
    const float* __restrict__ feats,
    const float* __restrict__ transitions,
    const int* __restrict__ tags,     // (B,T)
    const int* __restrict__ lengths,  // (B,)
    float* __restrict__ gold_out)     // (B,)
{
    const int b = blockIdx.x;
    const int lane = threadIdx.x;
    const int len = lengths[b];
    const int* tb = tags + b * Tt;
    const float* fb = feats + (size_t)b * Tt * Kk;

    float acc = 0.f;
    for (int t = lane; t < len; t += 64) {
        const int tg = tb[t];
        const int prev = (t == 0) ? START_TAG : tb[t - 1];
        acc += transitions[tg * Kk + prev];  // score prev -> tg
        acc += fb[t * Kk + tg];              // emission
    }
    if (lane == 0) acc += transitions[STOP_TAG * Kk + tb[len - 1]];  // last -> STOP
#pragma unroll
    for (int off = 32; off >= 1; off >>= 1) acc += __shfl_xor(acc, off, 64);
    if (lane == 0) gold_out[b] = acc;
}

__global__ __launch_bounds__(512) void crf_reduce_kernel(
    const float* __restrict__ fwd, const float* __restrict__ gold,
    float* __restrict__ out)
{
    const int i = threadIdx.x;  // 0..511
    float v = fwd[i] - gold[i];
#pragma unroll
    for (int off = 32; off >= 1; off >>= 1) v += __shfl_xor(v, off, 64);
    __shared__ float ws[8];
    if ((i & 63) == 0) ws[i >> 6] = v;
    __syncthreads();
    if (i < 8) {
        float s = ws[i];
#pragma unroll
        for (int off = 4; off >= 1; off >>= 1) s += __shfl_xor(s, off, 8);
        if (i == 0) out[0] = s * (1.0f / (float)Bb);
    }
}

extern "C" void kernel_launch(void* const* d_in, const int* in_sizes, int n_in,
                              void* d_out, int out_size, void* d_ws, size_t ws_size,
                              hipStream_t stream) {
    const float* feats = (const float*)d_in[0];
    const float* trans = (const float*)d_in[1];
    const int* tags = (const int*)d_in[2];
    const int* lengths = (const int*)d_in[3];
    float* out = (float*)d_out;
    float* fwd = (float*)d_ws;
    float* gold = fwd + Bb;

    crf_gold_kernel<<<Bb, 64, 0, stream>>>(feats, trans, tags, lengths, gold);
    crf_forward_mfma<<<Bb, 64, 0, stream>>>(feats, trans, lengths, fwd);
    crf_reduce_kernel<<<1, 512, 0, stream>>>(fwd, gold, out);
}